// Round 4
// baseline (161.590 us; speedup 1.0000x reference)
//
#include <hip/hip_runtime.h>
#include <hip/hip_bf16.h>

#define B_ 2
#define T_ 2048
#define E_ 1024
#define NH 16
#define M_ (B_*T_)   // 4096
#define N3E 3072

typedef __attribute__((ext_vector_type(8))) short short8;
typedef __attribute__((ext_vector_type(4))) float f32x4;
typedef __attribute__((ext_vector_type(4))) int int4v;

__device__ __forceinline__ unsigned short f2bf(float f) {
  unsigned u = __builtin_bit_cast(unsigned, f);
  unsigned r = 0x7FFFu + ((u >> 16) & 1u);
  return (unsigned short)((u + r) >> 16);
}

__device__ __forceinline__ float bf2f(unsigned short s) {
  return __builtin_bit_cast(float, ((unsigned)s) << 16);
}

__device__ __forceinline__ unsigned cvtpk(float a, float b) {
  unsigned r;
  asm("v_cvt_pk_bf16_f32 %0, %1, %2" : "=v"(r) : "v"(a), "v"(b));
  return r;
}

__device__ __forceinline__ float exp2fast(float x) {
  float r;
  asm("v_exp_f32 %0, %1" : "=v"(r) : "v"(x));
  return r;
}

__device__ __forceinline__ void gload16(const void* g, void* l) {
  __builtin_amdgcn_global_load_lds(
      (const __attribute__((address_space(1))) unsigned int*)g,
      (__attribute__((address_space(3))) unsigned int*)l, 16, 0, 0);
}

// ---- cast fp32 -> bf16 (elementwise), 8 elems/thread ----
__global__ void cast_kernel(const float* __restrict__ in,
                            unsigned short* __restrict__ out, int n8) {
  int i = blockIdx.x * blockDim.x + threadIdx.x;
  if (i >= n8) return;
  const float4* p = (const float4*)in + (size_t)i * 2;
  float4 a = p[0], b = p[1];
  short8 o;
  o[0] = (short)f2bf(a.x); o[1] = (short)f2bf(a.y);
  o[2] = (short)f2bf(a.z); o[3] = (short)f2bf(a.w);
  o[4] = (short)f2bf(b.x); o[5] = (short)f2bf(b.y);
  o[6] = (short)f2bf(b.z); o[7] = (short)f2bf(b.w);
  *(short8*)(out + (size_t)i * 8) = o;
}

// ---- transpose + cast: in (R x C) fp32 -> out (C x R) bf16 ----
__global__ void transpose_cast(const float* __restrict__ in,
                               unsigned short* __restrict__ out, int R, int C) {
  __shared__ float tile[32][33];
  int c0 = blockIdx.x * 32, r0 = blockIdx.y * 32;
  int tx = threadIdx.x & 31, ty = threadIdx.x >> 5;  // 32 x 8
#pragma unroll
  for (int i = 0; i < 4; i++) {
    int r = ty + i * 8;
    tile[r][tx] = in[(size_t)(r0 + r) * C + c0 + tx];
  }
  __syncthreads();
#pragma unroll
  for (int i = 0; i < 4; i++) {
    int r = ty + i * 8;
    out[(size_t)(c0 + r) * R + r0 + tx] = f2bf(tile[tx][r]);
  }
}

// ---- GEMM: A (MxK bf16 row-major) x Bt (NxK bf16 row-major) + bias -> out ----
template <int OUTF32>
__global__ __launch_bounds__(256) void gemm_bt(
    const unsigned short* __restrict__ A, const unsigned short* __restrict__ Bt,
    const float* __restrict__ bias, void* __restrict__ outp,
    int M, int N, int K) {
  __shared__ __attribute__((aligned(16))) unsigned short Asm[128 * 32];
  __shared__ __attribute__((aligned(16))) unsigned short Bsm[128 * 32];
  const int tid = threadIdx.x;
  const int lane = tid & 63;
  const int wid = tid >> 6;
  const int wr = wid >> 1, wc = wid & 1;
  const int li = lane & 15, g = lane >> 4;
  const int bm = blockIdx.y * 128, bn = blockIdx.x * 128;

  f32x4 acc[4][4] = {};

  const int srow = tid >> 2;
  const int scol = (tid & 3) * 8;
  const unsigned short* Ag = A + (size_t)(bm + srow) * K + scol;
  const unsigned short* Bg = Bt + (size_t)(bn + srow) * K + scol;
  char* AsmB = (char*)Asm;
  char* BsmB = (char*)Bsm;
  const int ldsoff = tid * 16;

  for (int k0 = 0; k0 < K; k0 += 32) {
    __syncthreads();
    gload16(Ag + k0, AsmB + ldsoff);
    gload16(Ag + (size_t)64 * K + k0, AsmB + ldsoff + 4096);
    gload16(Bg + k0, BsmB + ldsoff);
    gload16(Bg + (size_t)64 * K + k0, BsmB + ldsoff + 4096);
    __syncthreads();
    short8 af[4], bf[4];
#pragma unroll
    for (int i = 0; i < 4; i++)
      af[i] = *(const short8*)&Asm[(wr * 64 + i * 16 + li) * 32 + g * 8];
#pragma unroll
    for (int j = 0; j < 4; j++)
      bf[j] = *(const short8*)&Bsm[(wc * 64 + j * 16 + li) * 32 + g * 8];
#pragma unroll
    for (int i = 0; i < 4; i++)
#pragma unroll
      for (int j = 0; j < 4; j++)
        acc[i][j] = __builtin_amdgcn_mfma_f32_16x16x32_bf16(af[i], bf[j],
                                                            acc[i][j], 0, 0, 0);
  }

#pragma unroll
  for (int j = 0; j < 4; j++) {
    int col = bn + wc * 64 + j * 16 + li;
    float bs = bias[col];
#pragma unroll
    for (int i = 0; i < 4; i++) {
      int row0 = bm + wr * 64 + i * 16 + g * 4;
#pragma unroll
      for (int r = 0; r < 4; r++) {
        float v = acc[i][j][r] + bs;
        if (OUTF32)
          ((float*)outp)[(size_t)(row0 + r) * N + col] = v;
        else
          ((unsigned short*)outp)[(size_t)(row0 + r) * N + col] = f2bf(v);
      }
    }
  }
}

// ---- flash attention v4: single q-tile blocks, P exchange via ds_bpermute ----
__device__ __forceinline__ f32x4 mfma16(short8 a, short8 b, f32x4 c) {
  return __builtin_amdgcn_mfma_f32_16x16x32_bf16(a, b, c, 0, 0, 0);
}

// One 16q x 64s tile for one wave. Lane (li,g): q-row = li (lane-local m,l).
// S^T = mfma(Kfrag, Qfrag): lane holds S[q=li][s = ct*16+g*4+r].
// O^T = mfma(Vtfrag, Pfrag): lane holds O[q=li][d = c2*16+g*4+r].
__device__ __forceinline__ void attn_tile(
    const unsigned short* Ksm, const unsigned short* Vts,
    short8 qf0, short8 qf1, float& m2, float& l2, f32x4* O,
    int qrel, bool diag, int li, int g, int idx0, int idx1) {
  f32x4 S[4];
  __builtin_amdgcn_s_setprio(1);
#pragma unroll
  for (int ct = 0; ct < 4; ct++) {
    int r = ct * 16 + li;
    int sw = r & 7;
    short8 k0f = *(const short8*)&Ksm[r * 64 + ((g ^ sw) << 3)];
    short8 k1f = *(const short8*)&Ksm[r * 64 + (((g + 4) ^ sw) << 3)];
    f32x4 z = {0.f, 0.f, 0.f, 0.f};
    z = mfma16(k0f, qf0, z);
    z = mfma16(k1f, qf1, z);
    S[ct] = z;
  }
  __builtin_amdgcn_s_setprio(0);

  if (diag) {
#pragma unroll
    for (int ct = 0; ct < 4; ct++)
#pragma unroll
      for (int r = 0; r < 4; r++)
        if (ct * 16 + g * 4 + r > qrel) S[ct][r] = -30000.f;
  }

  float tmax = S[0][0];
#pragma unroll
  for (int ct = 0; ct < 4; ct++)
#pragma unroll
    for (int r = 0; r < 4; r++) tmax = fmaxf(tmax, S[ct][r]);
  tmax = fmaxf(tmax, __shfl_xor(tmax, 16));
  tmax = fmaxf(tmax, __shfl_xor(tmax, 32));

  if (__any(tmax > m2 + 11.5f)) {
    float mn = fmaxf(m2, tmax);
    float cs = exp2fast(m2 - mn);
    l2 *= cs;
#pragma unroll
    for (int c2 = 0; c2 < 4; c2++)
#pragma unroll
      for (int r = 0; r < 4; r++) O[c2][r] *= cs;
    m2 = mn;
  }

  // exp + pack P into registers: pk[ct] = bf16x4 of P[q=li][ct*16+g*4+..]
  unsigned pkx[4], pky[4];
  float rsum = 0.f;
#pragma unroll
  for (int ct = 0; ct < 4; ct++) {
    float p0 = exp2fast(S[ct][0] - m2);
    float p1 = exp2fast(S[ct][1] - m2);
    float p2 = exp2fast(S[ct][2] - m2);
    float p3 = exp2fast(S[ct][3] - m2);
    rsum += (p0 + p1) + (p2 + p3);
    pkx[ct] = cvtpk(p0, p1);
    pky[ct] = cvtpk(p2, p3);
  }
  rsum += __shfl_xor(rsum, 16);
  rsum += __shfl_xor(rsum, 32);
  l2 += rsum;

  // PV: assemble B-fragment via ds_bpermute from the 4 lanes sharing li.
  // lane g needs pk[2kk + (g>>1)] from lanes (2g)&3 (j=0..3) and (2g+1)&3 (j=4..7)
  const bool hi = ((g >> 1) & 1) != 0;
  __builtin_amdgcn_s_setprio(1);
#pragma unroll
  for (int kk = 0; kk < 2; kk++) {
    int aXl = __builtin_amdgcn_ds_bpermute(idx0, (int)pkx[2 * kk]);
    int aXh = __builtin_amdgcn_ds_bpermute(idx0, (int)pkx[2 * kk + 1]);
    int aYl = __builtin_amdgcn_ds_bpermute(idx0, (int)pky[2 * kk]);
    int aYh = __builtin_amdgcn_ds_bpermute(idx0, (int)pky[2 * kk + 1]);
    int bXl = __builtin_amdgcn_ds_bpermute(idx1, (int)pkx[2 * kk]);
    int bXh = __builtin_amdgcn_ds_bpermute(idx1, (int)pkx[2 * kk + 1]);
    int bYl = __builtin_amdgcn_ds_bpermute(idx1, (int)pky[2 * kk]);
    int bYh = __builtin_amdgcn_ds_bpermute(idx1, (int)pky[2 * kk + 1]);
    int4v u;
    u[0] = hi ? aXh : aXl;
    u[1] = hi ? aYh : aYl;
    u[2] = hi ? bXh : bXl;
    u[3] = hi ? bYh : bYl;
    short8 pf = __builtin_bit_cast(short8, u);
#pragma unroll
    for (int c2 = 0; c2 < 4; c2++) {
      int d = c2 * 16 + li;
      int swd = ((d >> 3) ^ d) & 7;
      short8 vf = *(const short8*)&Vts[d * 64 + (((kk * 4 + g) ^ swd) << 3)];
      O[c2] = mfma16(vf, pf, O[c2]);
    }
  }
  __builtin_amdgcn_s_setprio(0);
}

__global__ __launch_bounds__(256) void attn_kernel(
    const unsigned short* __restrict__ qkv, unsigned short* __restrict__ aout) {
  const int qt = (T_ / 64 - 1) - blockIdx.x;  // longest blocks first
  const int h = blockIdx.y, b = blockIdx.z;
  const int tid = threadIdx.x, lane = tid & 63, w = tid >> 6;
  const int li = lane & 15, g = lane >> 4;

  __shared__ __attribute__((aligned(16))) unsigned short Ksm[2][64 * 64];
  __shared__ __attribute__((aligned(16))) unsigned short Vts[2][64 * 64];

  const size_t rs = 3 * E_;
  const unsigned short* base = qkv + (size_t)b * T_ * rs + h * 64;
  const unsigned short* Kg = base + E_;
  const unsigned short* Vg = base + 2 * E_;

  const float QSC = 0.18033688f;  // 0.125 * log2(e)
  short8 qf0, qf1;
  {
    const unsigned short* qrow = base + (size_t)(qt * 64 + w * 16 + li) * rs;
    short8 v0 = *(const short8*)(qrow + g * 8);
    short8 v1 = *(const short8*)(qrow + 32 + g * 8);
#pragma unroll
    for (int j = 0; j < 8; j++) {
      qf0[j] = (short)f2bf(bf2f((unsigned short)v0[j]) * QSC);
      qf1[j] = (short)f2bf(bf2f((unsigned short)v1[j]) * QSC);
    }
  }

  const int idx0 = (li + 16 * ((2 * g) & 3)) * 4;
  const int idx1 = (li + 16 * ((2 * g + 1) & 3)) * 4;

  float m2 = -1e30f, l2 = 0.f;
  f32x4 O[4] = {};

  short8 vreg[2];

  // prologue: stage tile 0 into buffer 0
#pragma unroll
  for (int p = 0; p < 2; p++) {
    int idx = tid + p * 256;
    int r = idx >> 3, ch = idx & 7;
    int sc = (ch ^ (r & 7)) * 8;
    gload16(Kg + (size_t)r * rs + sc, (char*)&Ksm[0][0] + idx * 16);
  }
#pragma unroll
  for (int p = 0; p < 2; p++) {
    int idx = tid + p * 256;
    int r = idx >> 3, c = (idx & 7) * 8;
    vreg[p] = *(const short8*)(Vg + (size_t)r * rs + c);
  }
#pragma unroll
  for (int p = 0; p < 2; p++) {
    int idx = tid + p * 256;
    int r = idx >> 3, ch = idx & 7;
#pragma unroll
    for (int j = 0; j < 8; j++) {
      int d = ch * 8 + j;
      Vts[0][(d * 64 + r) ^ (((ch ^ j) & 7) << 3)] = (unsigned short)vreg[p][j];
    }
  }
  asm volatile("s_waitcnt vmcnt(0)" ::: "memory");
  __syncthreads();

  const int nt = qt + 1;
  for (int kv = 0; kv < nt; kv++) {
    const int cur = kv & 1, nxt = cur ^ 1;
    const bool pre = (kv + 1 < nt);
    if (pre) {
      const int s1 = (kv + 1) * 64;
#pragma unroll
      for (int p = 0; p < 2; p++) {
        int idx = tid + p * 256;
        int r = idx >> 3, c = (idx & 7) * 8;
        vreg[p] = *(const short8*)(Vg + (size_t)(s1 + r) * rs + c);
      }
#pragma unroll
      for (int p = 0; p < 2; p++) {
        int idx = tid + p * 256;
        int r = idx >> 3, ch = idx & 7;
        int sc = (ch ^ (r & 7)) * 8;
        gload16(Kg + (size_t)(s1 + r) * rs + sc,
                (char*)&Ksm[nxt][0] + idx * 16);
      }
    }

    attn_tile(&Ksm[cur][0], &Vts[cur][0], qf0, qf1, m2, l2, O,
              qt * 64 + w * 16 + li - kv * 64, kv == qt, li, g, idx0, idx1);

    if (pre) {
#pragma unroll
      for (int p = 0; p < 2; p++) {
        int idx = tid + p * 256;
        int r = idx >> 3, ch = idx & 7;
#pragma unroll
        for (int j = 0; j < 8; j++) {
          int d = ch * 8 + j;
          Vts[nxt][(d * 64 + r) ^ (((ch ^ j) & 7) << 3)] =
              (unsigned short)vreg[p][j];
        }
      }
    }
    asm volatile("s_waitcnt vmcnt(0)" ::: "memory");
    __syncthreads();
  }

  const float inv = 1.f / l2;
  const int row = b * T_ + qt * 64 + w * 16 + li;
#pragma unroll
  for (int c2 = 0; c2 < 4; c2++) {
    uint2 o;
    o.x = cvtpk(O[c2][0] * inv, O[c2][1] * inv);
    o.y = cvtpk(O[c2][2] * inv, O[c2][3] * inv);
    *(uint2*)&aout[(size_t)row * E_ + h * 64 + c2 * 16 + g * 4] = o;
  }
}

extern "C" void kernel_launch(void* const* d_in, const int* in_sizes, int n_in,
                              void* d_out, int out_size, void* d_ws,
                              size_t ws_size, hipStream_t stream) {
  const float* stacked = (const float*)d_in[0];
  const float* w_attn = (const float*)d_in[1];
  const float* b_attn = (const float*)d_in[2];
  const float* w_proj = (const float*)d_in[3];
  const float* b_proj = (const float*)d_in[4];
  float* out = (float*)d_out;

  unsigned short* Abf = (unsigned short*)d_ws;            // 4096x1024 bf16
  unsigned short* WaT = Abf + (size_t)M_ * E_;            // 3072x1024 bf16
  unsigned short* WpT = WaT + (size_t)N3E * E_;           // 1024x1024 bf16
  unsigned short* qkv = WpT + (size_t)E_ * E_;            // 4096x3072 bf16
  unsigned short* aout = qkv + (size_t)M_ * N3E;          // 4096x1024 bf16

  cast_kernel<<<(M_ * E_ / 8 + 255) / 256, 256, 0, stream>>>(stacked, Abf,
                                                             M_ * E_ / 8);
  transpose_cast<<<dim3(N3E / 32, E_ / 32), 256, 0, stream>>>(w_attn, WaT, E_,
                                                              N3E);
  transpose_cast<<<dim3(E_ / 32, E_ / 32), 256, 0, stream>>>(w_proj, WpT, E_,
                                                             E_);
  gemm_bt<0><<<dim3(N3E / 128, M_ / 128), 256, 0, stream>>>(Abf, WaT, b_attn,
                                                            qkv, M_, N3E, E_);
  attn_kernel<<<dim3(T_ / 64, NH, B_), 256, 0, stream>>>(qkv, aout);
  gemm_bt<1><<<dim3(E_ / 128, M_ / 128), 256, 0, stream>>>(aout, WpT, b_proj,
                                                           out, M_, E_, E_);
}

// Round 5
// 130.497 us; speedup vs baseline: 1.2383x; 1.2383x over previous
//
#include <hip/hip_runtime.h>
#include <hip/hip_bf16.h>

#define B_ 2
#define T_ 2048
#define E_ 1024
#define NH 16
#define M_ (B_*T_)   // 4096
#define N3E 3072

typedef __attribute__((ext_vector_type(8))) short short8;
typedef __attribute__((ext_vector_type(4))) float f32x4;

__device__ __forceinline__ unsigned short f2bf(float f) {
  unsigned u = __builtin_bit_cast(unsigned, f);
  unsigned r = 0x7FFFu + ((u >> 16) & 1u);
  return (unsigned short)((u + r) >> 16);
}

__device__ __forceinline__ float bf2f(unsigned short s) {
  return __builtin_bit_cast(float, ((unsigned)s) << 16);
}

__device__ __forceinline__ unsigned cvtpk(float a, float b) {
  unsigned r;
  asm("v_cvt_pk_bf16_f32 %0, %1, %2" : "=v"(r) : "v"(a), "v"(b));
  return r;
}

__device__ __forceinline__ float exp2fast(float x) {
  float r;
  asm("v_exp_f32 %0, %1" : "=v"(r) : "v"(x));
  return r;
}

__device__ __forceinline__ void gload16(const void* g, void* l) {
  __builtin_amdgcn_global_load_lds(
      (const __attribute__((address_space(1))) unsigned int*)g,
      (__attribute__((address_space(3))) unsigned int*)l, 16, 0, 0);
}

// ---- cast fp32 -> bf16 (elementwise), 8 elems/thread ----
__global__ void cast_kernel(const float* __restrict__ in,
                            unsigned short* __restrict__ out, int n8) {
  int i = blockIdx.x * blockDim.x + threadIdx.x;
  if (i >= n8) return;
  const float4* p = (const float4*)in + (size_t)i * 2;
  float4 a = p[0], b = p[1];
  short8 o;
  o[0] = (short)f2bf(a.x); o[1] = (short)f2bf(a.y);
  o[2] = (short)f2bf(a.z); o[3] = (short)f2bf(a.w);
  o[4] = (short)f2bf(b.x); o[5] = (short)f2bf(b.y);
  o[6] = (short)f2bf(b.z); o[7] = (short)f2bf(b.w);
  *(short8*)(out + (size_t)i * 8) = o;
}

// ---- transpose + cast: in (R x C) fp32 -> out (C x R) bf16 ----
__global__ void transpose_cast(const float* __restrict__ in,
                               unsigned short* __restrict__ out, int R, int C) {
  __shared__ float tile[32][33];
  int c0 = blockIdx.x * 32, r0 = blockIdx.y * 32;
  int tx = threadIdx.x & 31, ty = threadIdx.x >> 5;  // 32 x 8
#pragma unroll
  for (int i = 0; i < 4; i++) {
    int r = ty + i * 8;
    tile[r][tx] = in[(size_t)(r0 + r) * C + c0 + tx];
  }
  __syncthreads();
#pragma unroll
  for (int i = 0; i < 4; i++) {
    int r = ty + i * 8;
    out[(size_t)(c0 + r) * R + r0 + tx] = f2bf(tile[tx][r]);
  }
}

// ---- GEMM: A (MxK bf16 row-major) x Bt (NxK bf16 row-major) + bias -> out ----
template <int OUTF32>
__global__ __launch_bounds__(256) void gemm_bt(
    const unsigned short* __restrict__ A, const unsigned short* __restrict__ Bt,
    const float* __restrict__ bias, void* __restrict__ outp,
    int M, int N, int K) {
  __shared__ __attribute__((aligned(16))) unsigned short Asm[128 * 32];
  __shared__ __attribute__((aligned(16))) unsigned short Bsm[128 * 32];
  const int tid = threadIdx.x;
  const int lane = tid & 63;
  const int wid = tid >> 6;
  const int wr = wid >> 1, wc = wid & 1;
  const int li = lane & 15, g = lane >> 4;
  const int bm = blockIdx.y * 128, bn = blockIdx.x * 128;

  f32x4 acc[4][4] = {};

  const int srow = tid >> 2;
  const int scol = (tid & 3) * 8;
  const unsigned short* Ag = A + (size_t)(bm + srow) * K + scol;
  const unsigned short* Bg = Bt + (size_t)(bn + srow) * K + scol;
  char* AsmB = (char*)Asm;
  char* BsmB = (char*)Bsm;
  const int ldsoff = tid * 16;

  for (int k0 = 0; k0 < K; k0 += 32) {
    __syncthreads();
    gload16(Ag + k0, AsmB + ldsoff);
    gload16(Ag + (size_t)64 * K + k0, AsmB + ldsoff + 4096);
    gload16(Bg + k0, BsmB + ldsoff);
    gload16(Bg + (size_t)64 * K + k0, BsmB + ldsoff + 4096);
    __syncthreads();
    short8 af[4], bf[4];
#pragma unroll
    for (int i = 0; i < 4; i++)
      af[i] = *(const short8*)&Asm[(wr * 64 + i * 16 + li) * 32 + g * 8];
#pragma unroll
    for (int j = 0; j < 4; j++)
      bf[j] = *(const short8*)&Bsm[(wc * 64 + j * 16 + li) * 32 + g * 8];
#pragma unroll
    for (int i = 0; i < 4; i++)
#pragma unroll
      for (int j = 0; j < 4; j++)
        acc[i][j] = __builtin_amdgcn_mfma_f32_16x16x32_bf16(af[i], bf[j],
                                                            acc[i][j], 0, 0, 0);
  }

#pragma unroll
  for (int j = 0; j < 4; j++) {
    int col = bn + wc * 64 + j * 16 + li;
    float bs = bias[col];
#pragma unroll
    for (int i = 0; i < 4; i++) {
      int row0 = bm + wr * 64 + i * 16 + g * 4;
#pragma unroll
      for (int r = 0; r < 4; r++) {
        float v = acc[i][j][r] + bs;
        if (OUTF32)
          ((float*)outp)[(size_t)(row0 + r) * N + col] = v;
        else
          ((unsigned short*)outp)[(size_t)(row0 + r) * N + col] = f2bf(v);
      }
    }
  }
}

// ---- flash attention v5: R3 structure + swizzled Psm ----
__device__ __forceinline__ f32x4 mfma16(short8 a, short8 b, f32x4 c) {
  return __builtin_amdgcn_mfma_f32_16x16x32_bf16(a, b, c, 0, 0, 0);
}

// One 16q x 64s tile for one wave. Lane (li,g): q-row = li (lane-local m,l).
// S^T = mfma(Kfrag, Qfrag): lane holds S[q=li][s = ct*16+g*4+r].
// O^T = mfma(Vtfrag, Pfrag): lane holds O[q=li][d = c2*16+g*4+r].
// Psm rows are 64 elems (128B); 16B-chunk XOR-swizzled by (row&7).
__device__ __forceinline__ void attn_tile(
    const unsigned short* Ksm, const unsigned short* Vts,
    unsigned short (*PsmW)[64], short8 qf0, short8 qf1,
    float& m2, float& l2, f32x4* O, int qrel, bool diag, int li, int g) {
  f32x4 S[4];
  __builtin_amdgcn_s_setprio(1);
#pragma unroll
  for (int ct = 0; ct < 4; ct++) {
    int r = ct * 16 + li;
    int sw = r & 7;
    short8 k0f = *(const short8*)&Ksm[r * 64 + ((g ^ sw) << 3)];
    short8 k1f = *(const short8*)&Ksm[r * 64 + (((g + 4) ^ sw) << 3)];
    f32x4 z = {0.f, 0.f, 0.f, 0.f};
    z = mfma16(k0f, qf0, z);
    z = mfma16(k1f, qf1, z);
    S[ct] = z;
  }
  __builtin_amdgcn_s_setprio(0);

  if (diag) {
#pragma unroll
    for (int ct = 0; ct < 4; ct++)
#pragma unroll
      for (int r = 0; r < 4; r++)
        if (ct * 16 + g * 4 + r > qrel) S[ct][r] = -30000.f;
  }

  float tmax = S[0][0];
#pragma unroll
  for (int ct = 0; ct < 4; ct++)
#pragma unroll
    for (int r = 0; r < 4; r++) tmax = fmaxf(tmax, S[ct][r]);
  tmax = fmaxf(tmax, __shfl_xor(tmax, 16));
  tmax = fmaxf(tmax, __shfl_xor(tmax, 32));

  if (__any(tmax > m2 + 11.5f)) {
    float mn = fmaxf(m2, tmax);
    float cs = exp2fast(m2 - mn);
    l2 *= cs;
#pragma unroll
    for (int c2 = 0; c2 < 4; c2++)
#pragma unroll
      for (int r = 0; r < 4; r++) O[c2][r] *= cs;
    m2 = mn;
  }

  float rsum = 0.f;
#pragma unroll
  for (int ct = 0; ct < 4; ct++) {
    float p0 = exp2fast(S[ct][0] - m2);
    float p1 = exp2fast(S[ct][1] - m2);
    float p2 = exp2fast(S[ct][2] - m2);
    float p3 = exp2fast(S[ct][3] - m2);
    rsum += (p0 + p1) + (p2 + p3);
    uint2 pk;
    pk.x = cvtpk(p0, p1);
    pk.y = cvtpk(p2, p3);
    // logical elems x = ct*16+g*4 : chunk c = 2ct+(g>>1), half = g&1
    int pc = (2 * ct + (g >> 1)) ^ (li & 7);
    *(uint2*)&PsmW[li][pc * 8 + (g & 1) * 4] = pk;
  }
  rsum += __shfl_xor(rsum, 16);
  rsum += __shfl_xor(rsum, 32);
  l2 += rsum;

  __builtin_amdgcn_s_setprio(1);
#pragma unroll
  for (int kk = 0; kk < 2; kk++) {
    // logical elems x = kk*32+g*8 : chunk = 4kk+g
    short8 pf = *(const short8*)&PsmW[li][((4 * kk + g) ^ (li & 7)) * 8];
#pragma unroll
    for (int c2 = 0; c2 < 4; c2++) {
      int d = c2 * 16 + li;
      int swd = ((d >> 3) ^ d) & 7;
      short8 vf = *(const short8*)&Vts[d * 64 + (((kk * 4 + g) ^ swd) << 3)];
      O[c2] = mfma16(vf, pf, O[c2]);
    }
  }
  __builtin_amdgcn_s_setprio(0);
}

__global__ __launch_bounds__(256) void attn_kernel(
    const unsigned short* __restrict__ qkv, unsigned short* __restrict__ aout) {
  const int pair = blockIdx.x;  // 0..15
  const int h = blockIdx.y, b = blockIdx.z;
  const int qa = pair, qb = (T_ / 64 - 1) - pair;
  const int tid = threadIdx.x, lane = tid & 63, w = tid >> 6;
  const int li = lane & 15, g = lane >> 4;

  __shared__ __attribute__((aligned(16))) unsigned short Ksm[2][64 * 64];
  __shared__ __attribute__((aligned(16))) unsigned short Vts[2][64 * 64];
  __shared__ __attribute__((aligned(16))) unsigned short Psm[4][16][64];

  const size_t rs = 3 * E_;
  const unsigned short* base = qkv + (size_t)b * T_ * rs + h * 64;
  const unsigned short* Kg = base + E_;
  const unsigned short* Vg = base + 2 * E_;

  const float QSC = 0.18033688f;  // 0.125 * log2(e)
  short8 qfa0, qfa1, qfb0, qfb1;
  {
    const unsigned short* qrow = base + (size_t)(qa * 64 + w * 16 + li) * rs;
    short8 v0 = *(const short8*)(qrow + g * 8);
    short8 v1 = *(const short8*)(qrow + 32 + g * 8);
    qrow = base + (size_t)(qb * 64 + w * 16 + li) * rs;
    short8 v2 = *(const short8*)(qrow + g * 8);
    short8 v3 = *(const short8*)(qrow + 32 + g * 8);
#pragma unroll
    for (int j = 0; j < 8; j++) {
      qfa0[j] = (short)f2bf(bf2f((unsigned short)v0[j]) * QSC);
      qfa1[j] = (short)f2bf(bf2f((unsigned short)v1[j]) * QSC);
      qfb0[j] = (short)f2bf(bf2f((unsigned short)v2[j]) * QSC);
      qfb1[j] = (short)f2bf(bf2f((unsigned short)v3[j]) * QSC);
    }
  }

  float ma = -1e30f, la = 0.f, mb = -1e30f, lb = 0.f;
  f32x4 Oa[4] = {}, Ob[4] = {};

  short8 vreg[2];

  // prologue: stage tile 0 into buffer 0
#pragma unroll
  for (int p = 0; p < 2; p++) {
    int idx = tid + p * 256;
    int r = idx >> 3, ch = idx & 7;
    int sc = (ch ^ (r & 7)) * 8;
    gload16(Kg + (size_t)r * rs + sc, (char*)&Ksm[0][0] + idx * 16);
  }
#pragma unroll
  for (int p = 0; p < 2; p++) {
    int idx = tid + p * 256;
    int r = idx >> 3, c = (idx & 7) * 8;
    vreg[p] = *(const short8*)(Vg + (size_t)r * rs + c);
  }
#pragma unroll
  for (int p = 0; p < 2; p++) {
    int idx = tid + p * 256;
    int r = idx >> 3, ch = idx & 7;
#pragma unroll
    for (int j = 0; j < 8; j++) {
      int d = ch * 8 + j;
      Vts[0][(d * 64 + r) ^ (((ch ^ j) & 7) << 3)] = (unsigned short)vreg[p][j];
    }
  }
  asm volatile("s_waitcnt vmcnt(0)" ::: "memory");
  __syncthreads();

  const int nt = qb + 1;
  for (int kv = 0; kv < nt; kv++) {
    const int cur = kv & 1, nxt = cur ^ 1;
    const bool pre = (kv + 1 < nt);
    if (pre) {
      const int s1 = (kv + 1) * 64;
#pragma unroll
      for (int p = 0; p < 2; p++) {
        int idx = tid + p * 256;
        int r = idx >> 3, c = (idx & 7) * 8;
        vreg[p] = *(const short8*)(Vg + (size_t)(s1 + r) * rs + c);
      }
#pragma unroll
      for (int p = 0; p < 2; p++) {
        int idx = tid + p * 256;
        int r = idx >> 3, ch = idx & 7;
        int sc = (ch ^ (r & 7)) * 8;
        gload16(Kg + (size_t)(s1 + r) * rs + sc,
                (char*)&Ksm[nxt][0] + idx * 16);
      }
    }

    attn_tile(&Ksm[cur][0], &Vts[cur][0], Psm[w], qfb0, qfb1, mb, lb, Ob,
              qb * 64 + w * 16 + li - kv * 64, kv == qb, li, g);
    if (kv <= qa)
      attn_tile(&Ksm[cur][0], &Vts[cur][0], Psm[w], qfa0, qfa1, ma, la, Oa,
                qa * 64 + w * 16 + li - kv * 64, kv == qa, li, g);

    if (pre) {
#pragma unroll
      for (int p = 0; p < 2; p++) {
        int idx = tid + p * 256;
        int r = idx >> 3, ch = idx & 7;
#pragma unroll
        for (int j = 0; j < 8; j++) {
          int d = ch * 8 + j;
          Vts[nxt][(d * 64 + r) ^ (((ch ^ j) & 7) << 3)] =
              (unsigned short)vreg[p][j];
        }
      }
    }
    asm volatile("s_waitcnt vmcnt(0)" ::: "memory");
    __syncthreads();
  }

  const float inva = 1.f / la, invb = 1.f / lb;
  const int rowa = b * T_ + qa * 64 + w * 16 + li;
  const int rowb = b * T_ + qb * 64 + w * 16 + li;
#pragma unroll
  for (int c2 = 0; c2 < 4; c2++) {
    uint2 oa, ob;
    oa.x = cvtpk(Oa[c2][0] * inva, Oa[c2][1] * inva);
    oa.y = cvtpk(Oa[c2][2] * inva, Oa[c2][3] * inva);
    ob.x = cvtpk(Ob[c2][0] * invb, Ob[c2][1] * invb);
    ob.y = cvtpk(Ob[c2][2] * invb, Ob[c2][3] * invb);
    *(uint2*)&aout[(size_t)rowa * E_ + h * 64 + c2 * 16 + g * 4] = oa;
    *(uint2*)&aout[(size_t)rowb * E_ + h * 64 + c2 * 16 + g * 4] = ob;
  }
}

extern "C" void kernel_launch(void* const* d_in, const int* in_sizes, int n_in,
                              void* d_out, int out_size, void* d_ws,
                              size_t ws_size, hipStream_t stream) {
  const float* stacked = (const float*)d_in[0];
  const float* w_attn = (const float*)d_in[1];
  const float* b_attn = (const float*)d_in[2];
  const float* w_proj = (const float*)d_in[3];
  const float* b_proj = (const float*)d_in[4];
  float* out = (float*)d_out;

  unsigned short* Abf = (unsigned short*)d_ws;            // 4096x1024 bf16
  unsigned short* WaT = Abf + (size_t)M_ * E_;            // 3072x1024 bf16
  unsigned short* WpT = WaT + (size_t)N3E * E_;           // 1024x1024 bf16
  unsigned short* qkv = WpT + (size_t)E_ * E_;            // 4096x3072 bf16
  unsigned short* aout = qkv + (size_t)M_ * N3E;          // 4096x1024 bf16

  cast_kernel<<<(M_ * E_ / 8 + 255) / 256, 256, 0, stream>>>(stacked, Abf,
                                                             M_ * E_ / 8);
  transpose_cast<<<dim3(N3E / 32, E_ / 32), 256, 0, stream>>>(w_attn, WaT, E_,
                                                              N3E);
  transpose_cast<<<dim3(E_ / 32, E_ / 32), 256, 0, stream>>>(w_proj, WpT, E_,
                                                             E_);
  gemm_bt<0><<<dim3(N3E / 128, M_ / 128), 256, 0, stream>>>(Abf, WaT, b_attn,
                                                            qkv, M_, N3E, E_);
  attn_kernel<<<dim3(T_ / 128, NH, B_), 256, 0, stream>>>(qkv, aout);
  gemm_bt<1><<<dim3(E_ / 128, M_ / 128), 256, 0, stream>>>(aout, WpT, b_proj,
                                                           out, M_, E_, E_);
}

// Round 6
// 130.033 us; speedup vs baseline: 1.2427x; 1.0036x over previous
//
#include <hip/hip_runtime.h>
#include <hip/hip_bf16.h>

#define B_ 2
#define T_ 2048
#define E_ 1024
#define NH 16
#define M_ (B_*T_)   // 4096
#define N3E 3072

typedef __attribute__((ext_vector_type(8))) short short8;
typedef __attribute__((ext_vector_type(4))) float f32x4;

__device__ __forceinline__ unsigned short f2bf(float f) {
  unsigned u = __builtin_bit_cast(unsigned, f);
  unsigned r = 0x7FFFu + ((u >> 16) & 1u);
  return (unsigned short)((u + r) >> 16);
}

__device__ __forceinline__ float bf2f(unsigned short s) {
  return __builtin_bit_cast(float, ((unsigned)s) << 16);
}

__device__ __forceinline__ unsigned cvtpk(float a, float b) {
  unsigned r;
  asm("v_cvt_pk_bf16_f32 %0, %1, %2" : "=v"(r) : "v"(a), "v"(b));
  return r;
}

__device__ __forceinline__ float exp2fast(float x) {
  float r;
  asm("v_exp_f32 %0, %1" : "=v"(r) : "v"(x));
  return r;
}

__device__ __forceinline__ void gload16(const void* g, void* l) {
  __builtin_amdgcn_global_load_lds(
      (const __attribute__((address_space(1))) unsigned int*)g,
      (__attribute__((address_space(3))) unsigned int*)l, 16, 0, 0);
}

// ---- cast fp32 -> bf16 (elementwise), 8 elems/thread ----
__global__ void cast_kernel(const float* __restrict__ in,
                            unsigned short* __restrict__ out, int n8) {
  int i = blockIdx.x * blockDim.x + threadIdx.x;
  if (i >= n8) return;
  const float4* p = (const float4*)in + (size_t)i * 2;
  float4 a = p[0], b = p[1];
  short8 o;
  o[0] = (short)f2bf(a.x); o[1] = (short)f2bf(a.y);
  o[2] = (short)f2bf(a.z); o[3] = (short)f2bf(a.w);
  o[4] = (short)f2bf(b.x); o[5] = (short)f2bf(b.y);
  o[6] = (short)f2bf(b.z); o[7] = (short)f2bf(b.w);
  *(short8*)(out + (size_t)i * 8) = o;
}

// ---- transpose + cast: in (R x C) fp32 -> out (C x R) bf16 ----
__global__ void transpose_cast(const float* __restrict__ in,
                               unsigned short* __restrict__ out, int R, int C) {
  __shared__ float tile[32][33];
  int c0 = blockIdx.x * 32, r0 = blockIdx.y * 32;
  int tx = threadIdx.x & 31, ty = threadIdx.x >> 5;  // 32 x 8
#pragma unroll
  for (int i = 0; i < 4; i++) {
    int r = ty + i * 8;
    tile[r][tx] = in[(size_t)(r0 + r) * C + c0 + tx];
  }
  __syncthreads();
#pragma unroll
  for (int i = 0; i < 4; i++) {
    int r = ty + i * 8;
    out[(size_t)(c0 + r) * R + r0 + tx] = f2bf(tile[tx][r]);
  }
}

// ---- V transpose: qkv V-part (b, s, c) -> Vt (b, c, s), bf16 ----
__global__ __launch_bounds__(256) void vtrans_kernel(
    const unsigned short* __restrict__ qkv, unsigned short* __restrict__ Vt) {
  const int s0 = blockIdx.x * 64;
  const int c0 = blockIdx.y * 64;
  const int b = blockIdx.z;
  __shared__ unsigned short t[64][72];
  const int tid = threadIdx.x;
  const size_t rs = 3 * E_;
  const unsigned short* src = qkv + (size_t)(b * T_) * rs + 2 * E_;
#pragma unroll
  for (int p = 0; p < 2; p++) {
    int idx = tid + p * 256;
    int r = idx >> 3, c = (idx & 7) * 8;
    *(short8*)&t[r][c] = *(const short8*)(src + (size_t)(s0 + r) * rs + c0 + c);
  }
  __syncthreads();
#pragma unroll
  for (int p = 0; p < 2; p++) {
    int idx = tid + p * 256;
    int dr = idx >> 3, sc = (idx & 7) * 8;
    short8 o;
#pragma unroll
    for (int j = 0; j < 8; j++) o[j] = (short)t[sc + j][dr];
    *(short8*)&Vt[(size_t)(b * E_ + c0 + dr) * T_ + s0 + sc] = o;
  }
}

// ---- GEMM: A (MxK bf16 row-major) x Bt (NxK bf16 row-major) + bias -> out ----
template <int OUTF32>
__global__ __launch_bounds__(256) void gemm_bt(
    const unsigned short* __restrict__ A, const unsigned short* __restrict__ Bt,
    const float* __restrict__ bias, void* __restrict__ outp,
    int M, int N, int K) {
  __shared__ __attribute__((aligned(16))) unsigned short Asm[128 * 32];
  __shared__ __attribute__((aligned(16))) unsigned short Bsm[128 * 32];
  const int tid = threadIdx.x;
  const int lane = tid & 63;
  const int wid = tid >> 6;
  const int wr = wid >> 1, wc = wid & 1;
  const int li = lane & 15, g = lane >> 4;
  const int bm = blockIdx.y * 128, bn = blockIdx.x * 128;

  f32x4 acc[4][4] = {};

  const int srow = tid >> 2;
  const int scol = (tid & 3) * 8;
  const unsigned short* Ag = A + (size_t)(bm + srow) * K + scol;
  const unsigned short* Bg = Bt + (size_t)(bn + srow) * K + scol;
  char* AsmB = (char*)Asm;
  char* BsmB = (char*)Bsm;
  const int ldsoff = tid * 16;

  for (int k0 = 0; k0 < K; k0 += 32) {
    __syncthreads();
    gload16(Ag + k0, AsmB + ldsoff);
    gload16(Ag + (size_t)64 * K + k0, AsmB + ldsoff + 4096);
    gload16(Bg + k0, BsmB + ldsoff);
    gload16(Bg + (size_t)64 * K + k0, BsmB + ldsoff + 4096);
    __syncthreads();
    short8 af[4], bf[4];
#pragma unroll
    for (int i = 0; i < 4; i++)
      af[i] = *(const short8*)&Asm[(wr * 64 + i * 16 + li) * 32 + g * 8];
#pragma unroll
    for (int j = 0; j < 4; j++)
      bf[j] = *(const short8*)&Bsm[(wc * 64 + j * 16 + li) * 32 + g * 8];
#pragma unroll
    for (int i = 0; i < 4; i++)
#pragma unroll
      for (int j = 0; j < 4; j++)
        acc[i][j] = __builtin_amdgcn_mfma_f32_16x16x32_bf16(af[i], bf[j],
                                                            acc[i][j], 0, 0, 0);
  }

#pragma unroll
  for (int j = 0; j < 4; j++) {
    int col = bn + wc * 64 + j * 16 + li;
    float bs = bias[col];
#pragma unroll
    for (int i = 0; i < 4; i++) {
      int row0 = bm + wr * 64 + i * 16 + g * 4;
#pragma unroll
      for (int r = 0; r < 4; r++) {
        float v = acc[i][j][r] + bs;
        if (OUTF32)
          ((float*)outp)[(size_t)(row0 + r) * N + col] = v;
        else
          ((unsigned short*)outp)[(size_t)(row0 + r) * N + col] = f2bf(v);
      }
    }
  }
}

// ---- flash attention v6: V pre-transposed, all staging via global_load_lds ----
__device__ __forceinline__ f32x4 mfma16(short8 a, short8 b, f32x4 c) {
  return __builtin_amdgcn_mfma_f32_16x16x32_bf16(a, b, c, 0, 0, 0);
}

// One 16q x 64s tile for one wave. Lane (li,g): q-row = li (lane-local m,l).
// S^T = mfma(Kfrag, Qfrag): lane holds S[q=li][s = ct*16+g*4+r].
// O^T = mfma(Vtfrag, Pfrag): lane holds O[q=li][d = c2*16+g*4+r].
__device__ __forceinline__ void attn_tile(
    const unsigned short* Ksm, const unsigned short* Vts,
    unsigned short (*PsmW)[64], short8 qf0, short8 qf1,
    float& m2, float& l2, f32x4* O, int qrel, bool diag, int li, int g) {
  f32x4 S[4];
  __builtin_amdgcn_s_setprio(1);
#pragma unroll
  for (int ct = 0; ct < 4; ct++) {
    int r = ct * 16 + li;
    int sw = r & 7;
    short8 k0f = *(const short8*)&Ksm[r * 64 + ((g ^ sw) << 3)];
    short8 k1f = *(const short8*)&Ksm[r * 64 + (((g + 4) ^ sw) << 3)];
    f32x4 z = {0.f, 0.f, 0.f, 0.f};
    z = mfma16(k0f, qf0, z);
    z = mfma16(k1f, qf1, z);
    S[ct] = z;
  }
  __builtin_amdgcn_s_setprio(0);

  if (diag) {
#pragma unroll
    for (int ct = 0; ct < 4; ct++)
#pragma unroll
      for (int r = 0; r < 4; r++)
        if (ct * 16 + g * 4 + r > qrel) S[ct][r] = -30000.f;
  }

  float tmax = S[0][0];
#pragma unroll
  for (int ct = 0; ct < 4; ct++)
#pragma unroll
    for (int r = 0; r < 4; r++) tmax = fmaxf(tmax, S[ct][r]);
  tmax = fmaxf(tmax, __shfl_xor(tmax, 16));
  tmax = fmaxf(tmax, __shfl_xor(tmax, 32));

  if (__any(tmax > m2 + 11.5f)) {
    float mn = fmaxf(m2, tmax);
    float cs = exp2fast(m2 - mn);
    l2 *= cs;
#pragma unroll
    for (int c2 = 0; c2 < 4; c2++)
#pragma unroll
      for (int r = 0; r < 4; r++) O[c2][r] *= cs;
    m2 = mn;
  }

  float rsum = 0.f;
#pragma unroll
  for (int ct = 0; ct < 4; ct++) {
    float p0 = exp2fast(S[ct][0] - m2);
    float p1 = exp2fast(S[ct][1] - m2);
    float p2 = exp2fast(S[ct][2] - m2);
    float p3 = exp2fast(S[ct][3] - m2);
    rsum += (p0 + p1) + (p2 + p3);
    uint2 pk;
    pk.x = cvtpk(p0, p1);
    pk.y = cvtpk(p2, p3);
    int pc = (2 * ct + (g >> 1)) ^ (li & 7);
    *(uint2*)&PsmW[li][pc * 8 + (g & 1) * 4] = pk;
  }
  rsum += __shfl_xor(rsum, 16);
  rsum += __shfl_xor(rsum, 32);
  l2 += rsum;

  __builtin_amdgcn_s_setprio(1);
#pragma unroll
  for (int kk = 0; kk < 2; kk++) {
    short8 pf = *(const short8*)&PsmW[li][((4 * kk + g) ^ (li & 7)) * 8];
#pragma unroll
    for (int c2 = 0; c2 < 4; c2++) {
      int d = c2 * 16 + li;
      short8 vf = *(const short8*)&Vts[d * 64 + (((kk * 4 + g) ^ (li & 7)) << 3)];
      O[c2] = mfma16(vf, pf, O[c2]);
    }
  }
  __builtin_amdgcn_s_setprio(0);
}

__global__ __launch_bounds__(256) void attn_kernel(
    const unsigned short* __restrict__ qkv, const unsigned short* __restrict__ Vt,
    unsigned short* __restrict__ aout) {
  const int pair = blockIdx.x;  // 0..15
  const int h = blockIdx.y, b = blockIdx.z;
  const int qa = pair, qb = (T_ / 64 - 1) - pair;
  const int tid = threadIdx.x, lane = tid & 63, w = tid >> 6;
  const int li = lane & 15, g = lane >> 4;

  __shared__ __attribute__((aligned(16))) unsigned short Ksm[2][64 * 64];
  __shared__ __attribute__((aligned(16))) unsigned short Vts[2][64 * 64];
  __shared__ __attribute__((aligned(16))) unsigned short Psm[4][16][64];

  const size_t rs = 3 * E_;
  const unsigned short* base = qkv + (size_t)b * T_ * rs + h * 64;
  const unsigned short* Kg = base + E_;
  const unsigned short* Vtg = Vt + (size_t)(b * E_ + h * 64) * T_;

  const float QSC = 0.18033688f;  // 0.125 * log2(e)
  short8 qfa0, qfa1, qfb0, qfb1;
  {
    const unsigned short* qrow = base + (size_t)(qa * 64 + w * 16 + li) * rs;
    short8 v0 = *(const short8*)(qrow + g * 8);
    short8 v1 = *(const short8*)(qrow + 32 + g * 8);
    qrow = base + (size_t)(qb * 64 + w * 16 + li) * rs;
    short8 v2 = *(const short8*)(qrow + g * 8);
    short8 v3 = *(const short8*)(qrow + 32 + g * 8);
#pragma unroll
    for (int j = 0; j < 8; j++) {
      qfa0[j] = (short)f2bf(bf2f((unsigned short)v0[j]) * QSC);
      qfa1[j] = (short)f2bf(bf2f((unsigned short)v1[j]) * QSC);
      qfb0[j] = (short)f2bf(bf2f((unsigned short)v2[j]) * QSC);
      qfb1[j] = (short)f2bf(bf2f((unsigned short)v3[j]) * QSC);
    }
  }

  float ma = -1e30f, la = 0.f, mb = -1e30f, lb = 0.f;
  f32x4 Oa[4] = {}, Ob[4] = {};

  // prologue: stage tile 0 into buffer 0 (K rows + Vt rows, both swizzled src)
#pragma unroll
  for (int p = 0; p < 2; p++) {
    int idx = tid + p * 256;
    int r = idx >> 3, ch = idx & 7;
    int sc = (ch ^ (r & 7)) * 8;
    gload16(Kg + (size_t)r * rs + sc, (char*)&Ksm[0][0] + idx * 16);
    gload16(Vtg + (size_t)r * T_ + sc, (char*)&Vts[0][0] + idx * 16);
  }
  asm volatile("s_waitcnt vmcnt(0)" ::: "memory");
  __syncthreads();

  const int nt = qb + 1;
  for (int kv = 0; kv < nt; kv++) {
    const int cur = kv & 1, nxt = cur ^ 1;
    const bool pre = (kv + 1 < nt);
    if (pre) {
      const int s1 = (kv + 1) * 64;
#pragma unroll
      for (int p = 0; p < 2; p++) {
        int idx = tid + p * 256;
        int r = idx >> 3, ch = idx & 7;
        int sc = (ch ^ (r & 7)) * 8;
        gload16(Kg + (size_t)(s1 + r) * rs + sc,
                (char*)&Ksm[nxt][0] + idx * 16);
        gload16(Vtg + (size_t)r * T_ + s1 + sc,
                (char*)&Vts[nxt][0] + idx * 16);
      }
    }

    attn_tile(&Ksm[cur][0], &Vts[cur][0], Psm[w], qfb0, qfb1, mb, lb, Ob,
              qb * 64 + w * 16 + li - kv * 64, kv == qb, li, g);
    if (kv <= qa)
      attn_tile(&Ksm[cur][0], &Vts[cur][0], Psm[w], qfa0, qfa1, ma, la, Oa,
                qa * 64 + w * 16 + li - kv * 64, kv == qa, li, g);

    asm volatile("s_waitcnt vmcnt(0)" ::: "memory");
    __syncthreads();
  }

  const float inva = 1.f / la, invb = 1.f / lb;
  const int rowa = b * T_ + qa * 64 + w * 16 + li;
  const int rowb = b * T_ + qb * 64 + w * 16 + li;
#pragma unroll
  for (int c2 = 0; c2 < 4; c2++) {
    uint2 oa, ob;
    oa.x = cvtpk(Oa[c2][0] * inva, Oa[c2][1] * inva);
    oa.y = cvtpk(Oa[c2][2] * inva, Oa[c2][3] * inva);
    ob.x = cvtpk(Ob[c2][0] * invb, Ob[c2][1] * invb);
    ob.y = cvtpk(Ob[c2][2] * invb, Ob[c2][3] * invb);
    *(uint2*)&aout[(size_t)rowa * E_ + h * 64 + c2 * 16 + g * 4] = oa;
    *(uint2*)&aout[(size_t)rowb * E_ + h * 64 + c2 * 16 + g * 4] = ob;
  }
}

extern "C" void kernel_launch(void* const* d_in, const int* in_sizes, int n_in,
                              void* d_out, int out_size, void* d_ws,
                              size_t ws_size, hipStream_t stream) {
  const float* stacked = (const float*)d_in[0];
  const float* w_attn = (const float*)d_in[1];
  const float* b_attn = (const float*)d_in[2];
  const float* w_proj = (const float*)d_in[3];
  const float* b_proj = (const float*)d_in[4];
  float* out = (float*)d_out;

  unsigned short* Abf = (unsigned short*)d_ws;            // 4096x1024 bf16
  unsigned short* WaT = Abf + (size_t)M_ * E_;            // 3072x1024 bf16
  unsigned short* WpT = WaT + (size_t)N3E * E_;           // 1024x1024 bf16
  unsigned short* qkv = WpT + (size_t)E_ * E_;            // 4096x3072 bf16
  unsigned short* aout = qkv + (size_t)M_ * N3E;          // 4096x1024 bf16
  unsigned short* Vt = aout + (size_t)M_ * E_;            // 2x1024x2048 bf16

  cast_kernel<<<(M_ * E_ / 8 + 255) / 256, 256, 0, stream>>>(stacked, Abf,
                                                             M_ * E_ / 8);
  transpose_cast<<<dim3(N3E / 32, E_ / 32), 256, 0, stream>>>(w_attn, WaT, E_,
                                                              N3E);
  transpose_cast<<<dim3(E_ / 32, E_ / 32), 256, 0, stream>>>(w_proj, WpT, E_,
                                                             E_);
  gemm_bt<0><<<dim3(N3E / 128, M_ / 128), 256, 0, stream>>>(Abf, WaT, b_attn,
                                                            qkv, M_, N3E, E_);
  vtrans_kernel<<<dim3(T_ / 64, E_ / 64, B_), 256, 0, stream>>>(qkv, Vt);
  attn_kernel<<<dim3(T_ / 128, NH, B_), 256, 0, stream>>>(qkv, Vt, aout);
  gemm_bt<1><<<dim3(E_ / 128, M_ / 128), 256, 0, stream>>>(aout, WpT, b_proj,
                                                           out, M_, E_, E_);
}

// Round 7
// 127.312 us; speedup vs baseline: 1.2692x; 1.0214x over previous
//
#include <hip/hip_runtime.h>
#include <hip/hip_bf16.h>

#define B_ 2
#define T_ 2048
#define E_ 1024
#define NH 16
#define M_ (B_*T_)   // 4096
#define N3E 3072

typedef __attribute__((ext_vector_type(8))) short short8;
typedef __attribute__((ext_vector_type(4))) float f32x4;

__device__ __forceinline__ unsigned short f2bf(float f) {
  unsigned u = __builtin_bit_cast(unsigned, f);
  unsigned r = 0x7FFFu + ((u >> 16) & 1u);
  return (unsigned short)((u + r) >> 16);
}

__device__ __forceinline__ float bf2f(unsigned short s) {
  return __builtin_bit_cast(float, ((unsigned)s) << 16);
}

__device__ __forceinline__ unsigned cvtpk(float a, float b) {
  unsigned r;
  asm("v_cvt_pk_bf16_f32 %0, %1, %2" : "=v"(r) : "v"(a), "v"(b));
  return r;
}

__device__ __forceinline__ float exp2fast(float x) {
  float r;
  asm("v_exp_f32 %0, %1" : "=v"(r) : "v"(x));
  return r;
}

__device__ __forceinline__ void gload16(const void* g, void* l) {
  __builtin_amdgcn_global_load_lds(
      (const __attribute__((address_space(1))) unsigned int*)g,
      (__attribute__((address_space(3))) unsigned int*)l, 16, 0, 0);
}

// ---- merged prep: cast stacked->bf16, transpose+cast both weights ----
// blocks [0,2048): cast; [2048,5120): w_attn T; [5120,6144): w_proj T
__global__ __launch_bounds__(256) void prep_kernel(
    const float* __restrict__ stacked, const float* __restrict__ w_attn,
    const float* __restrict__ w_proj, unsigned short* __restrict__ Abf,
    unsigned short* __restrict__ WaT, unsigned short* __restrict__ WpT) {
  __shared__ float tile[32][33];
  const int bx = blockIdx.x;
  const int tid = threadIdx.x;
  if (bx < 2048) {
    int i = bx * 256 + tid;
    const float4* p = (const float4*)stacked + (size_t)i * 2;
    float4 a = p[0], b = p[1];
    short8 o;
    o[0] = (short)f2bf(a.x); o[1] = (short)f2bf(a.y);
    o[2] = (short)f2bf(a.z); o[3] = (short)f2bf(a.w);
    o[4] = (short)f2bf(b.x); o[5] = (short)f2bf(b.y);
    o[6] = (short)f2bf(b.z); o[7] = (short)f2bf(b.w);
    *(short8*)(Abf + (size_t)i * 8) = o;
    return;
  }
  const float* in;
  unsigned short* out;
  int R, C, c0, r0;
  if (bx < 5120) {
    int b = bx - 2048;
    in = w_attn; out = WaT; R = E_; C = N3E;
    c0 = (b % 96) * 32; r0 = (b / 96) * 32;
  } else {
    int b = bx - 5120;
    in = w_proj; out = WpT; R = E_; C = E_;
    c0 = (b % 32) * 32; r0 = (b / 32) * 32;
  }
  int tx = tid & 31, ty = tid >> 5;  // 32 x 8
#pragma unroll
  for (int i = 0; i < 4; i++) {
    int r = ty + i * 8;
    tile[r][tx] = in[(size_t)(r0 + r) * C + c0 + tx];
  }
  __syncthreads();
#pragma unroll
  for (int i = 0; i < 4; i++) {
    int r = ty + i * 8;
    out[(size_t)(c0 + r) * R + r0 + tx] = f2bf(tile[tx][r]);
  }
}

// ---- V transpose: qkv V-part (b, s, c) -> Vt (b, c, s), bf16 ----
__global__ __launch_bounds__(256) void vtrans_kernel(
    const unsigned short* __restrict__ qkv, unsigned short* __restrict__ Vt) {
  const int s0 = blockIdx.x * 64;
  const int c0 = blockIdx.y * 64;
  const int b = blockIdx.z;
  __shared__ unsigned short t[64][72];
  const int tid = threadIdx.x;
  const size_t rs = 3 * E_;
  const unsigned short* src = qkv + (size_t)(b * T_) * rs + 2 * E_;
#pragma unroll
  for (int p = 0; p < 2; p++) {
    int idx = tid + p * 256;
    int r = idx >> 3, c = (idx & 7) * 8;
    *(short8*)&t[r][c] = *(const short8*)(src + (size_t)(s0 + r) * rs + c0 + c);
  }
  __syncthreads();
#pragma unroll
  for (int p = 0; p < 2; p++) {
    int idx = tid + p * 256;
    int dr = idx >> 3, sc = (idx & 7) * 8;
    short8 o;
#pragma unroll
    for (int j = 0; j < 8; j++) o[j] = (short)t[sc + j][dr];
    *(short8*)&Vt[(size_t)(b * E_ + c0 + dr) * T_ + s0 + sc] = o;
  }
}

// ---- GEMM v2: BK=64, XOR-swizzled LDS, XCD-swizzled grid ----
// A (MxK bf16 rm) x Bt (NxK bf16 rm) + bias -> out. 128x128 tile, 4 waves.
template <int OUTF32>
__global__ __launch_bounds__(256) void gemm_bt(
    const unsigned short* __restrict__ A, const unsigned short* __restrict__ Bt,
    const float* __restrict__ bias, void* __restrict__ outp,
    int M, int N, int K) {
  __shared__ __attribute__((aligned(16))) unsigned short Asm[128 * 64];
  __shared__ __attribute__((aligned(16))) unsigned short Bsm[128 * 64];
  const int tid = threadIdx.x;
  const int lane = tid & 63;
  const int wid = tid >> 6;
  const int wr = wid >> 1, wc = wid & 1;
  const int li = lane & 15, g = lane >> 4;

  // XCD-aware bijective swizzle (grids here are multiples of 8)
  const int ntx = N >> 7;
  const int nwg = (M >> 7) * ntx;
  const int cpx = nwg >> 3;
  const int logical = (blockIdx.x & 7) * cpx + (blockIdx.x >> 3);
  const int bm = (logical / ntx) << 7;
  const int bn = (logical % ntx) << 7;

  f32x4 acc[4][4] = {};

  for (int k0 = 0; k0 < K; k0 += 64) {
    __syncthreads();
#pragma unroll
    for (int p = 0; p < 4; p++) {
      int idx = tid + p * 256;
      int r = idx >> 3, ch = idx & 7;
      int sc = (ch ^ (r & 7)) << 3;
      gload16(A + (size_t)(bm + r) * K + k0 + sc, (char*)Asm + idx * 16);
      gload16(Bt + (size_t)(bn + r) * K + k0 + sc, (char*)Bsm + idx * 16);
    }
    __syncthreads();
#pragma unroll
    for (int kk = 0; kk < 2; kk++) {
      short8 af[4], bf[4];
#pragma unroll
      for (int i = 0; i < 4; i++) {
        int R = wr * 64 + i * 16 + li;
        af[i] = *(const short8*)&Asm[R * 64 + (((kk * 4 + g) ^ (R & 7)) << 3)];
      }
#pragma unroll
      for (int j = 0; j < 4; j++) {
        int R = wc * 64 + j * 16 + li;
        bf[j] = *(const short8*)&Bsm[R * 64 + (((kk * 4 + g) ^ (R & 7)) << 3)];
      }
#pragma unroll
      for (int i = 0; i < 4; i++)
#pragma unroll
        for (int j = 0; j < 4; j++)
          acc[i][j] = __builtin_amdgcn_mfma_f32_16x16x32_bf16(
              af[i], bf[j], acc[i][j], 0, 0, 0);
    }
  }

#pragma unroll
  for (int j = 0; j < 4; j++) {
    int col = bn + wc * 64 + j * 16 + li;
    float bs = bias[col];
#pragma unroll
    for (int i = 0; i < 4; i++) {
      int row0 = bm + wr * 64 + i * 16 + g * 4;
#pragma unroll
      for (int r = 0; r < 4; r++) {
        float v = acc[i][j][r] + bs;
        if (OUTF32)
          ((float*)outp)[(size_t)(row0 + r) * N + col] = v;
        else
          ((unsigned short*)outp)[(size_t)(row0 + r) * N + col] = f2bf(v);
      }
    }
  }
}

// ---- flash attention v6: V pre-transposed, all staging via global_load_lds ----
__device__ __forceinline__ f32x4 mfma16(short8 a, short8 b, f32x4 c) {
  return __builtin_amdgcn_mfma_f32_16x16x32_bf16(a, b, c, 0, 0, 0);
}

__device__ __forceinline__ void attn_tile(
    const unsigned short* Ksm, const unsigned short* Vts,
    unsigned short (*PsmW)[64], short8 qf0, short8 qf1,
    float& m2, float& l2, f32x4* O, int qrel, bool diag, int li, int g) {
  f32x4 S[4];
  __builtin_amdgcn_s_setprio(1);
#pragma unroll
  for (int ct = 0; ct < 4; ct++) {
    int r = ct * 16 + li;
    int sw = r & 7;
    short8 k0f = *(const short8*)&Ksm[r * 64 + ((g ^ sw) << 3)];
    short8 k1f = *(const short8*)&Ksm[r * 64 + (((g + 4) ^ sw) << 3)];
    f32x4 z = {0.f, 0.f, 0.f, 0.f};
    z = mfma16(k0f, qf0, z);
    z = mfma16(k1f, qf1, z);
    S[ct] = z;
  }
  __builtin_amdgcn_s_setprio(0);

  if (diag) {
#pragma unroll
    for (int ct = 0; ct < 4; ct++)
#pragma unroll
      for (int r = 0; r < 4; r++)
        if (ct * 16 + g * 4 + r > qrel) S[ct][r] = -30000.f;
  }

  float tmax = S[0][0];
#pragma unroll
  for (int ct = 0; ct < 4; ct++)
#pragma unroll
    for (int r = 0; r < 4; r++) tmax = fmaxf(tmax, S[ct][r]);
  tmax = fmaxf(tmax, __shfl_xor(tmax, 16));
  tmax = fmaxf(tmax, __shfl_xor(tmax, 32));

  if (__any(tmax > m2 + 11.5f)) {
    float mn = fmaxf(m2, tmax);
    float cs = exp2fast(m2 - mn);
    l2 *= cs;
#pragma unroll
    for (int c2 = 0; c2 < 4; c2++)
#pragma unroll
      for (int r = 0; r < 4; r++) O[c2][r] *= cs;
    m2 = mn;
  }

  float rsum = 0.f;
#pragma unroll
  for (int ct = 0; ct < 4; ct++) {
    float p0 = exp2fast(S[ct][0] - m2);
    float p1 = exp2fast(S[ct][1] - m2);
    float p2 = exp2fast(S[ct][2] - m2);
    float p3 = exp2fast(S[ct][3] - m2);
    rsum += (p0 + p1) + (p2 + p3);
    uint2 pk;
    pk.x = cvtpk(p0, p1);
    pk.y = cvtpk(p2, p3);
    int pc = (2 * ct + (g >> 1)) ^ (li & 7);
    *(uint2*)&PsmW[li][pc * 8 + (g & 1) * 4] = pk;
  }
  rsum += __shfl_xor(rsum, 16);
  rsum += __shfl_xor(rsum, 32);
  l2 += rsum;

  __builtin_amdgcn_s_setprio(1);
#pragma unroll
  for (int kk = 0; kk < 2; kk++) {
    short8 pf = *(const short8*)&PsmW[li][((4 * kk + g) ^ (li & 7)) * 8];
#pragma unroll
    for (int c2 = 0; c2 < 4; c2++) {
      int d = c2 * 16 + li;
      short8 vf = *(const short8*)&Vts[d * 64 + (((kk * 4 + g) ^ (li & 7)) << 3)];
      O[c2] = mfma16(vf, pf, O[c2]);
    }
  }
  __builtin_amdgcn_s_setprio(0);
}

__global__ __launch_bounds__(256) void attn_kernel(
    const unsigned short* __restrict__ qkv, const unsigned short* __restrict__ Vt,
    unsigned short* __restrict__ aout) {
  const int pair = blockIdx.x;  // 0..15
  const int h = blockIdx.y, b = blockIdx.z;
  const int qa = pair, qb = (T_ / 64 - 1) - pair;
  const int tid = threadIdx.x, lane = tid & 63, w = tid >> 6;
  const int li = lane & 15, g = lane >> 4;

  __shared__ __attribute__((aligned(16))) unsigned short Ksm[2][64 * 64];
  __shared__ __attribute__((aligned(16))) unsigned short Vts[2][64 * 64];
  __shared__ __attribute__((aligned(16))) unsigned short Psm[4][16][64];

  const size_t rs = 3 * E_;
  const unsigned short* base = qkv + (size_t)b * T_ * rs + h * 64;
  const unsigned short* Kg = base + E_;
  const unsigned short* Vtg = Vt + (size_t)(b * E_ + h * 64) * T_;

  const float QSC = 0.18033688f;  // 0.125 * log2(e)
  short8 qfa0, qfa1, qfb0, qfb1;
  {
    const unsigned short* qrow = base + (size_t)(qa * 64 + w * 16 + li) * rs;
    short8 v0 = *(const short8*)(qrow + g * 8);
    short8 v1 = *(const short8*)(qrow + 32 + g * 8);
    qrow = base + (size_t)(qb * 64 + w * 16 + li) * rs;
    short8 v2 = *(const short8*)(qrow + g * 8);
    short8 v3 = *(const short8*)(qrow + 32 + g * 8);
#pragma unroll
    for (int j = 0; j < 8; j++) {
      qfa0[j] = (short)f2bf(bf2f((unsigned short)v0[j]) * QSC);
      qfa1[j] = (short)f2bf(bf2f((unsigned short)v1[j]) * QSC);
      qfb0[j] = (short)f2bf(bf2f((unsigned short)v2[j]) * QSC);
      qfb1[j] = (short)f2bf(bf2f((unsigned short)v3[j]) * QSC);
    }
  }

  float ma = -1e30f, la = 0.f, mb = -1e30f, lb = 0.f;
  f32x4 Oa[4] = {}, Ob[4] = {};

#pragma unroll
  for (int p = 0; p < 2; p++) {
    int idx = tid + p * 256;
    int r = idx >> 3, ch = idx & 7;
    int sc = (ch ^ (r & 7)) * 8;
    gload16(Kg + (size_t)r * rs + sc, (char*)&Ksm[0][0] + idx * 16);
    gload16(Vtg + (size_t)r * T_ + sc, (char*)&Vts[0][0] + idx * 16);
  }
  asm volatile("s_waitcnt vmcnt(0)" ::: "memory");
  __syncthreads();

  const int nt = qb + 1;
  for (int kv = 0; kv < nt; kv++) {
    const int cur = kv & 1, nxt = cur ^ 1;
    const bool pre = (kv + 1 < nt);
    if (pre) {
      const int s1 = (kv + 1) * 64;
#pragma unroll
      for (int p = 0; p < 2; p++) {
        int idx = tid + p * 256;
        int r = idx >> 3, ch = idx & 7;
        int sc = (ch ^ (r & 7)) * 8;
        gload16(Kg + (size_t)(s1 + r) * rs + sc,
                (char*)&Ksm[nxt][0] + idx * 16);
        gload16(Vtg + (size_t)r * T_ + s1 + sc,
                (char*)&Vts[nxt][0] + idx * 16);
      }
    }

    attn_tile(&Ksm[cur][0], &Vts[cur][0], Psm[w], qfb0, qfb1, mb, lb, Ob,
              qb * 64 + w * 16 + li - kv * 64, kv == qb, li, g);
    if (kv <= qa)
      attn_tile(&Ksm[cur][0], &Vts[cur][0], Psm[w], qfa0, qfa1, ma, la, Oa,
                qa * 64 + w * 16 + li - kv * 64, kv == qa, li, g);

    asm volatile("s_waitcnt vmcnt(0)" ::: "memory");
    __syncthreads();
  }

  const float inva = 1.f / la, invb = 1.f / lb;
  const int rowa = b * T_ + qa * 64 + w * 16 + li;
  const int rowb = b * T_ + qb * 64 + w * 16 + li;
#pragma unroll
  for (int c2 = 0; c2 < 4; c2++) {
    uint2 oa, ob;
    oa.x = cvtpk(Oa[c2][0] * inva, Oa[c2][1] * inva);
    oa.y = cvtpk(Oa[c2][2] * inva, Oa[c2][3] * inva);
    ob.x = cvtpk(Ob[c2][0] * invb, Ob[c2][1] * invb);
    ob.y = cvtpk(Ob[c2][2] * invb, Ob[c2][3] * invb);
    *(uint2*)&aout[(size_t)rowa * E_ + h * 64 + c2 * 16 + g * 4] = oa;
    *(uint2*)&aout[(size_t)rowb * E_ + h * 64 + c2 * 16 + g * 4] = ob;
  }
}

extern "C" void kernel_launch(void* const* d_in, const int* in_sizes, int n_in,
                              void* d_out, int out_size, void* d_ws,
                              size_t ws_size, hipStream_t stream) {
  const float* stacked = (const float*)d_in[0];
  const float* w_attn = (const float*)d_in[1];
  const float* b_attn = (const float*)d_in[2];
  const float* w_proj = (const float*)d_in[3];
  const float* b_proj = (const float*)d_in[4];
  float* out = (float*)d_out;

  unsigned short* Abf = (unsigned short*)d_ws;            // 4096x1024 bf16
  unsigned short* WaT = Abf + (size_t)M_ * E_;            // 3072x1024 bf16
  unsigned short* WpT = WaT + (size_t)N3E * E_;           // 1024x1024 bf16
  unsigned short* qkv = WpT + (size_t)E_ * E_;            // 4096x3072 bf16
  unsigned short* aout = qkv + (size_t)M_ * N3E;          // 4096x1024 bf16
  unsigned short* Vt = aout + (size_t)M_ * E_;            // 2x1024x2048 bf16

  prep_kernel<<<6144, 256, 0, stream>>>(stacked, w_attn, w_proj, Abf, WaT, WpT);
  gemm_bt<0><<<(M_ / 128) * (N3E / 128), 256, 0, stream>>>(Abf, WaT, b_attn,
                                                           qkv, M_, N3E, E_);
  vtrans_kernel<<<dim3(T_ / 64, E_ / 64, B_), 256, 0, stream>>>(qkv, Vt);
  attn_kernel<<<dim3(T_ / 128, NH, B_), 256, 0, stream>>>(qkv, Vt, aout);
  gemm_bt<1><<<(M_ / 128) * (E_ / 128), 256, 0, stream>>>(aout, WpT, b_proj,
                                                          out, M_, E_, E_);
}

// Round 8
// 120.463 us; speedup vs baseline: 1.3414x; 1.0569x over previous
//
#include <hip/hip_runtime.h>
#include <hip/hip_bf16.h>

#define B_ 2
#define T_ 2048
#define E_ 1024
#define NH 16
#define M_ (B_*T_)   // 4096
#define N3E 3072

typedef __attribute__((ext_vector_type(8))) short short8;
typedef __attribute__((ext_vector_type(4))) float f32x4;

__device__ __forceinline__ unsigned short f2bf(float f) {
  unsigned u = __builtin_bit_cast(unsigned, f);
  unsigned r = 0x7FFFu + ((u >> 16) & 1u);
  return (unsigned short)((u + r) >> 16);
}

__device__ __forceinline__ float bf2f(unsigned short s) {
  return __builtin_bit_cast(float, ((unsigned)s) << 16);
}

__device__ __forceinline__ unsigned cvtpk(float a, float b) {
  unsigned r;
  asm("v_cvt_pk_bf16_f32 %0, %1, %2" : "=v"(r) : "v"(a), "v"(b));
  return r;
}

__device__ __forceinline__ float exp2fast(float x) {
  float r;
  asm("v_exp_f32 %0, %1" : "=v"(r) : "v"(x));
  return r;
}

__device__ __forceinline__ void gload16(const void* g, void* l) {
  __builtin_amdgcn_global_load_lds(
      (const __attribute__((address_space(1))) unsigned int*)g,
      (__attribute__((address_space(3))) unsigned int*)l, 16, 0, 0);
}

// ---- merged prep: cast stacked->bf16, transpose+cast both weights ----
// blocks [0,2048): cast; [2048,5120): w_attn T; [5120,6144): w_proj T
__global__ __launch_bounds__(256) void prep_kernel(
    const float* __restrict__ stacked, const float* __restrict__ w_attn,
    const float* __restrict__ w_proj, unsigned short* __restrict__ Abf,
    unsigned short* __restrict__ WaT, unsigned short* __restrict__ WpT) {
  __shared__ float tile[32][33];
  const int bx = blockIdx.x;
  const int tid = threadIdx.x;
  if (bx < 2048) {
    int i = bx * 256 + tid;
    const float4* p = (const float4*)stacked + (size_t)i * 2;
    float4 a = p[0], b = p[1];
    short8 o;
    o[0] = (short)f2bf(a.x); o[1] = (short)f2bf(a.y);
    o[2] = (short)f2bf(a.z); o[3] = (short)f2bf(a.w);
    o[4] = (short)f2bf(b.x); o[5] = (short)f2bf(b.y);
    o[6] = (short)f2bf(b.z); o[7] = (short)f2bf(b.w);
    *(short8*)(Abf + (size_t)i * 8) = o;
    return;
  }
  const float* in;
  unsigned short* out;
  int R, C, c0, r0;
  if (bx < 5120) {
    int b = bx - 2048;
    in = w_attn; out = WaT; R = E_; C = N3E;
    c0 = (b % 96) * 32; r0 = (b / 96) * 32;
  } else {
    int b = bx - 5120;
    in = w_proj; out = WpT; R = E_; C = E_;
    c0 = (b % 32) * 32; r0 = (b / 32) * 32;
  }
  int tx = tid & 31, ty = tid >> 5;  // 32 x 8
#pragma unroll
  for (int i = 0; i < 4; i++) {
    int r = ty + i * 8;
    tile[r][tx] = in[(size_t)(r0 + r) * C + c0 + tx];
  }
  __syncthreads();
#pragma unroll
  for (int i = 0; i < 4; i++) {
    int r = ty + i * 8;
    out[(size_t)(c0 + r) * R + r0 + tx] = f2bf(tile[tx][r]);
  }
}

// ---- V transpose: qkv V-part (b, s, c) -> Vt (b, c, s), bf16 ----
__global__ __launch_bounds__(256) void vtrans_kernel(
    const unsigned short* __restrict__ qkv, unsigned short* __restrict__ Vt) {
  const int s0 = blockIdx.x * 64;
  const int c0 = blockIdx.y * 64;
  const int b = blockIdx.z;
  __shared__ unsigned short t[64][72];
  const int tid = threadIdx.x;
  const size_t rs = 3 * E_;
  const unsigned short* src = qkv + (size_t)(b * T_) * rs + 2 * E_;
#pragma unroll
  for (int p = 0; p < 2; p++) {
    int idx = tid + p * 256;
    int r = idx >> 3, c = (idx & 7) * 8;
    *(short8*)&t[r][c] = *(const short8*)(src + (size_t)(s0 + r) * rs + c0 + c);
  }
  __syncthreads();
#pragma unroll
  for (int p = 0; p < 2; p++) {
    int idx = tid + p * 256;
    int dr = idx >> 3, sc = (idx & 7) * 8;
    short8 o;
#pragma unroll
    for (int j = 0; j < 8; j++) o[j] = (short)t[sc + j][dr];
    *(short8*)&Vt[(size_t)(b * E_ + c0 + dr) * T_ + s0 + sc] = o;
  }
}

// ---- GEMM v3: BK=32, 2-phase prefetch double-buffer, XCD-swizzled grid ----
// A (MxK bf16 rm) x Bt (NxK bf16 rm) + bias -> out. 128x128 tile, 4 waves.
template <int OUTF32>
__global__ __launch_bounds__(256) void gemm_bt(
    const unsigned short* __restrict__ A, const unsigned short* __restrict__ Bt,
    const float* __restrict__ bias, void* __restrict__ outp,
    int M, int N, int K) {
  __shared__ __attribute__((aligned(16))) unsigned short Asm[2][128 * 32];
  __shared__ __attribute__((aligned(16))) unsigned short Bsm[2][128 * 32];
  const int tid = threadIdx.x;
  const int lane = tid & 63;
  const int wid = tid >> 6;
  const int wr = wid >> 1, wc = wid & 1;
  const int li = lane & 15, g = lane >> 4;

  // XCD-aware bijective swizzle (grids here are multiples of 8)
  const int ntx = N >> 7;
  const int nwg = (M >> 7) * ntx;
  const int cpx = nwg >> 3;
  const int logical = (blockIdx.x & 7) * cpx + (blockIdx.x >> 3);
  const int bm = (logical / ntx) << 7;
  const int bn = (logical % ntx) << 7;

  f32x4 acc[4][4] = {};

  const int srow = tid >> 2;
  const int scol = (tid & 3) * 8;
  const unsigned short* Ag = A + (size_t)(bm + srow) * K + scol;
  const unsigned short* Bg = Bt + (size_t)(bn + srow) * K + scol;
  const int ldsoff = tid * 16;

  // prologue: stage k0=0 into buffer 0
  gload16(Ag, (char*)&Asm[0][0] + ldsoff);
  gload16(Ag + (size_t)64 * K, (char*)&Asm[0][0] + ldsoff + 4096);
  gload16(Bg, (char*)&Bsm[0][0] + ldsoff);
  gload16(Bg + (size_t)64 * K, (char*)&Bsm[0][0] + ldsoff + 4096);
  asm volatile("s_waitcnt vmcnt(0)" ::: "memory");
  __syncthreads();

  int cur = 0;
  for (int k0 = 0; k0 < K; k0 += 32) {
    const bool pre = (k0 + 32 < K);
    if (pre) {
      const int k1 = k0 + 32;
      gload16(Ag + k1, (char*)&Asm[cur ^ 1][0] + ldsoff);
      gload16(Ag + (size_t)64 * K + k1,
              (char*)&Asm[cur ^ 1][0] + ldsoff + 4096);
      gload16(Bg + k1, (char*)&Bsm[cur ^ 1][0] + ldsoff);
      gload16(Bg + (size_t)64 * K + k1,
              (char*)&Bsm[cur ^ 1][0] + ldsoff + 4096);
    }
    short8 af[4], bf[4];
#pragma unroll
    for (int i = 0; i < 4; i++)
      af[i] = *(const short8*)&Asm[cur][(wr * 64 + i * 16 + li) * 32 + g * 8];
#pragma unroll
    for (int j = 0; j < 4; j++)
      bf[j] = *(const short8*)&Bsm[cur][(wc * 64 + j * 16 + li) * 32 + g * 8];
    __builtin_amdgcn_s_setprio(1);
#pragma unroll
    for (int i = 0; i < 4; i++)
#pragma unroll
      for (int j = 0; j < 4; j++)
        acc[i][j] = __builtin_amdgcn_mfma_f32_16x16x32_bf16(af[i], bf[j],
                                                            acc[i][j], 0, 0, 0);
    __builtin_amdgcn_s_setprio(0);
    if (pre) asm volatile("s_waitcnt vmcnt(0)" ::: "memory");
    __syncthreads();
    cur ^= 1;
  }

#pragma unroll
  for (int j = 0; j < 4; j++) {
    int col = bn + wc * 64 + j * 16 + li;
    float bs = bias[col];
#pragma unroll
    for (int i = 0; i < 4; i++) {
      int row0 = bm + wr * 64 + i * 16 + g * 4;
#pragma unroll
      for (int r = 0; r < 4; r++) {
        float v = acc[i][j][r] + bs;
        if (OUTF32)
          ((float*)outp)[(size_t)(row0 + r) * N + col] = v;
        else
          ((unsigned short*)outp)[(size_t)(row0 + r) * N + col] = f2bf(v);
      }
    }
  }
}

// ---- flash attention v6: V pre-transposed, all staging via global_load_lds ----
__device__ __forceinline__ f32x4 mfma16(short8 a, short8 b, f32x4 c) {
  return __builtin_amdgcn_mfma_f32_16x16x32_bf16(a, b, c, 0, 0, 0);
}

__device__ __forceinline__ void attn_tile(
    const unsigned short* Ksm, const unsigned short* Vts,
    unsigned short (*PsmW)[64], short8 qf0, short8 qf1,
    float& m2, float& l2, f32x4* O, int qrel, bool diag, int li, int g) {
  f32x4 S[4];
  __builtin_amdgcn_s_setprio(1);
#pragma unroll
  for (int ct = 0; ct < 4; ct++) {
    int r = ct * 16 + li;
    int sw = r & 7;
    short8 k0f = *(const short8*)&Ksm[r * 64 + ((g ^ sw) << 3)];
    short8 k1f = *(const short8*)&Ksm[r * 64 + (((g + 4) ^ sw) << 3)];
    f32x4 z = {0.f, 0.f, 0.f, 0.f};
    z = mfma16(k0f, qf0, z);
    z = mfma16(k1f, qf1, z);
    S[ct] = z;
  }
  __builtin_amdgcn_s_setprio(0);

  if (diag) {
#pragma unroll
    for (int ct = 0; ct < 4; ct++)
#pragma unroll
      for (int r = 0; r < 4; r++)
        if (ct * 16 + g * 4 + r > qrel) S[ct][r] = -30000.f;
  }

  float tmax = S[0][0];
#pragma unroll
  for (int ct = 0; ct < 4; ct++)
#pragma unroll
    for (int r = 0; r < 4; r++) tmax = fmaxf(tmax, S[ct][r]);
  tmax = fmaxf(tmax, __shfl_xor(tmax, 16));
  tmax = fmaxf(tmax, __shfl_xor(tmax, 32));

  if (__any(tmax > m2 + 11.5f)) {
    float mn = fmaxf(m2, tmax);
    float cs = exp2fast(m2 - mn);
    l2 *= cs;
#pragma unroll
    for (int c2 = 0; c2 < 4; c2++)
#pragma unroll
      for (int r = 0; r < 4; r++) O[c2][r] *= cs;
    m2 = mn;
  }

  float rsum = 0.f;
#pragma unroll
  for (int ct = 0; ct < 4; ct++) {
    float p0 = exp2fast(S[ct][0] - m2);
    float p1 = exp2fast(S[ct][1] - m2);
    float p2 = exp2fast(S[ct][2] - m2);
    float p3 = exp2fast(S[ct][3] - m2);
    rsum += (p0 + p1) + (p2 + p3);
    uint2 pk;
    pk.x = cvtpk(p0, p1);
    pk.y = cvtpk(p2, p3);
    int pc = (2 * ct + (g >> 1)) ^ (li & 7);
    *(uint2*)&PsmW[li][pc * 8 + (g & 1) * 4] = pk;
  }
  rsum += __shfl_xor(rsum, 16);
  rsum += __shfl_xor(rsum, 32);
  l2 += rsum;

  __builtin_amdgcn_s_setprio(1);
#pragma unroll
  for (int kk = 0; kk < 2; kk++) {
    short8 pf = *(const short8*)&PsmW[li][((4 * kk + g) ^ (li & 7)) * 8];
#pragma unroll
    for (int c2 = 0; c2 < 4; c2++) {
      int d = c2 * 16 + li;
      short8 vf = *(const short8*)&Vts[d * 64 + (((kk * 4 + g) ^ (li & 7)) << 3)];
      O[c2] = mfma16(vf, pf, O[c2]);
    }
  }
  __builtin_amdgcn_s_setprio(0);
}

__global__ __launch_bounds__(256) void attn_kernel(
    const unsigned short* __restrict__ qkv, const unsigned short* __restrict__ Vt,
    unsigned short* __restrict__ aout) {
  const int pair = blockIdx.x;  // 0..15
  const int h = blockIdx.y, b = blockIdx.z;
  const int qa = pair, qb = (T_ / 64 - 1) - pair;
  const int tid = threadIdx.x, lane = tid & 63, w = tid >> 6;
  const int li = lane & 15, g = lane >> 4;

  __shared__ __attribute__((aligned(16))) unsigned short Ksm[2][64 * 64];
  __shared__ __attribute__((aligned(16))) unsigned short Vts[2][64 * 64];
  __shared__ __attribute__((aligned(16))) unsigned short Psm[4][16][64];

  const size_t rs = 3 * E_;
  const unsigned short* base = qkv + (size_t)b * T_ * rs + h * 64;
  const unsigned short* Kg = base + E_;
  const unsigned short* Vtg = Vt + (size_t)(b * E_ + h * 64) * T_;

  const float QSC = 0.18033688f;  // 0.125 * log2(e)
  short8 qfa0, qfa1, qfb0, qfb1;
  {
    const unsigned short* qrow = base + (size_t)(qa * 64 + w * 16 + li) * rs;
    short8 v0 = *(const short8*)(qrow + g * 8);
    short8 v1 = *(const short8*)(qrow + 32 + g * 8);
    qrow = base + (size_t)(qb * 64 + w * 16 + li) * rs;
    short8 v2 = *(const short8*)(qrow + g * 8);
    short8 v3 = *(const short8*)(qrow + 32 + g * 8);
#pragma unroll
    for (int j = 0; j < 8; j++) {
      qfa0[j] = (short)f2bf(bf2f((unsigned short)v0[j]) * QSC);
      qfa1[j] = (short)f2bf(bf2f((unsigned short)v1[j]) * QSC);
      qfb0[j] = (short)f2bf(bf2f((unsigned short)v2[j]) * QSC);
      qfb1[j] = (short)f2bf(bf2f((unsigned short)v3[j]) * QSC);
    }
  }

  float ma = -1e30f, la = 0.f, mb = -1e30f, lb = 0.f;
  f32x4 Oa[4] = {}, Ob[4] = {};

#pragma unroll
  for (int p = 0; p < 2; p++) {
    int idx = tid + p * 256;
    int r = idx >> 3, ch = idx & 7;
    int sc = (ch ^ (r & 7)) * 8;
    gload16(Kg + (size_t)r * rs + sc, (char*)&Ksm[0][0] + idx * 16);
    gload16(Vtg + (size_t)r * T_ + sc, (char*)&Vts[0][0] + idx * 16);
  }
  asm volatile("s_waitcnt vmcnt(0)" ::: "memory");
  __syncthreads();

  const int nt = qb + 1;
  for (int kv = 0; kv < nt; kv++) {
    const int cur = kv & 1, nxt = cur ^ 1;
    const bool pre = (kv + 1 < nt);
    if (pre) {
      const int s1 = (kv + 1) * 64;
#pragma unroll
      for (int p = 0; p < 2; p++) {
        int idx = tid + p * 256;
        int r = idx >> 3, ch = idx & 7;
        int sc = (ch ^ (r & 7)) * 8;
        gload16(Kg + (size_t)(s1 + r) * rs + sc,
                (char*)&Ksm[nxt][0] + idx * 16);
        gload16(Vtg + (size_t)r * T_ + s1 + sc,
                (char*)&Vts[nxt][0] + idx * 16);
      }
    }

    attn_tile(&Ksm[cur][0], &Vts[cur][0], Psm[w], qfb0, qfb1, mb, lb, Ob,
              qb * 64 + w * 16 + li - kv * 64, kv == qb, li, g);
    if (kv <= qa)
      attn_tile(&Ksm[cur][0], &Vts[cur][0], Psm[w], qfa0, qfa1, ma, la, Oa,
                qa * 64 + w * 16 + li - kv * 64, kv == qa, li, g);

    asm volatile("s_waitcnt vmcnt(0)" ::: "memory");
    __syncthreads();
  }

  const float inva = 1.f / la, invb = 1.f / lb;
  const int rowa = b * T_ + qa * 64 + w * 16 + li;
  const int rowb = b * T_ + qb * 64 + w * 16 + li;
#pragma unroll
  for (int c2 = 0; c2 < 4; c2++) {
    uint2 oa, ob;
    oa.x = cvtpk(Oa[c2][0] * inva, Oa[c2][1] * inva);
    oa.y = cvtpk(Oa[c2][2] * inva, Oa[c2][3] * inva);
    ob.x = cvtpk(Ob[c2][0] * invb, Ob[c2][1] * invb);
    ob.y = cvtpk(Ob[c2][2] * invb, Ob[c2][3] * invb);
    *(uint2*)&aout[(size_t)rowa * E_ + h * 64 + c2 * 16 + g * 4] = oa;
    *(uint2*)&aout[(size_t)rowb * E_ + h * 64 + c2 * 16 + g * 4] = ob;
  }
}

extern "C" void kernel_launch(void* const* d_in, const int* in_sizes, int n_in,
                              void* d_out, int out_size, void* d_ws,
                              size_t ws_size, hipStream_t stream) {
  const float* stacked = (const float*)d_in[0];
  const float* w_attn = (const float*)d_in[1];
  const float* b_attn = (const float*)d_in[2];
  const float* w_proj = (const float*)d_in[3];
  const float* b_proj = (const float*)d_in[4];
  float* out = (float*)d_out;

  unsigned short* Abf = (unsigned short*)d_ws;            // 4096x1024 bf16
  unsigned short* WaT = Abf + (size_t)M_ * E_;            // 3072x1024 bf16
  unsigned short* WpT = WaT + (size_t)N3E * E_;           // 1024x1024 bf16
  unsigned short* qkv = WpT + (size_t)E_ * E_;            // 4096x3072 bf16
  unsigned short* aout = qkv + (size_t)M_ * N3E;          // 4096x1024 bf16
  unsigned short* Vt = aout + (size_t)M_ * E_;            // 2x1024x2048 bf16

  prep_kernel<<<6144, 256, 0, stream>>>(stacked, w_attn, w_proj, Abf, WaT, WpT);
  gemm_bt<0><<<(M_ / 128) * (N3E / 128), 256, 0, stream>>>(Abf, WaT, b_attn,
                                                           qkv, M_, N3E, E_);
  vtrans_kernel<<<dim3(T_ / 64, E_ / 64, B_), 256, 0, stream>>>(qkv, Vt);
  attn_kernel<<<dim3(T_ / 128, NH, B_), 256, 0, stream>>>(qkv, Vt, aout);
  gemm_bt<1><<<(M_ / 128) * (E_ / 128), 256, 0, stream>>>(aout, WpT, b_proj,
                                                          out, M_, E_, E_);
}